// Round 4
// baseline (490.208 us; speedup 1.0000x reference)
//
#include <hip/hip_runtime.h>
#include <math.h>

#define NPTS 262144
#define KC 512
#define DD 64
#define MARGIN 0.02f

typedef _Float16 f16x8 __attribute__((ext_vector_type(8)));
typedef float f32x4 __attribute__((ext_vector_type(4)));

// d_ws layout (bytes)
#define WS_CNT   0      // int counter
#define WS_CS16  16     // 512 f32: c_sq + 16
#define WS_CSQ   2064   // 512 f32: exact c_sq (pairwise-8, for cleanup)
#define WS_CF16  4112   // 512*64 f16
#define WS_LIST  69648  // flagged point indices

__device__ __forceinline__ float csq_pairwise8(const float* row) {
    float r[8];
#pragma unroll
    for (int t = 0; t < 8; ++t) r[t] = __fmul_rn(row[t], row[t]);
#pragma unroll
    for (int b = 1; b < 8; ++b)
#pragma unroll
        for (int t = 0; t < 8; ++t)
            r[t] = __fadd_rn(r[t], __fmul_rn(row[8 * b + t], row[8 * b + t]));
    return __fadd_rn(__fadd_rn(__fadd_rn(r[0], r[1]), __fadd_rn(r[2], r[3])),
                     __fadd_rn(__fadd_rn(r[4], r[5]), __fadd_rn(r[6], r[7])));
}

// Prep: centroid passthrough to out, f16 conversion, c_sq (exact) and c_sq+16.
__global__ __launch_bounds__(256) void prep_kernel(const float* __restrict__ c,
                                                   float* __restrict__ out_c,
                                                   _Float16* __restrict__ cf16,
                                                   float* __restrict__ cs16,
                                                   float* __restrict__ csq) {
    int j = blockIdx.x * 256 + threadIdx.x;
    if (j < KC * DD) {
        float v = c[j];
        out_c[j] = v;
        cf16[j] = (_Float16)v;  // RNE
    }
    if (j < KC) {
        float s = csq_pairwise8(c + j * DD);
        csq[j] = s;
        cs16[j] = s + 16.0f;
    }
}

// Approx filter: per wave 32 points x 512 centroids via mfma_f32_16x16x32_f16.
// d'(k) = (c_sq[k]+16) - 2*cross_f16  (per-point shift by x_sq+16-x_sq drops out
// of both argmin and gaps). Best-2 tracked as packed keys (distbits&~0x1FF)|k:
// d' in [5.6,27] > 0 so uint-min is order-correct; ties pick smallest k.
// Gap <= MARGIN -> flag for exact rescore.
__global__ __launch_bounds__(256, 2) void approx_kernel(const float* __restrict__ x,
                                                        const _Float16* __restrict__ cf16,
                                                        const float* __restrict__ cs16g,
                                                        float* __restrict__ out_assign,
                                                        int* __restrict__ cnt,
                                                        int* __restrict__ list,
                                                        int list_cap) {
    extern __shared__ char smem[];                  // [0,64K): swizzled c_f16; [64K,64K+2K): cs16
    float* scs = (float*)(smem + 65536);

    int tid = threadIdx.x;
    // Stage centroids f16, XOR-swizzled (T2): row stride 128B would be a 16-way
    // bank conflict on ds_read_b128; slot ^= (row&7) spreads 8 rows over 8 slots.
    const uint4* src = (const uint4*)cf16;
#pragma unroll
    for (int i = 0; i < 16; ++i) {
        int chunk = tid + i * 256;          // 4096 chunks of 16B
        int row = chunk >> 3, slot = chunk & 7;
        uint4 v = src[chunk];
        *(uint4*)(smem + row * 128 + ((slot ^ (row & 7)) << 4)) = v;
    }
    scs[tid] = cs16g[tid];
    scs[tid + 256] = cs16g[tid + 256];
    __syncthreads();

    int wid = tid >> 6, lane = tid & 63;
    int pbase = blockIdx.x * 128 + wid * 32;
    int lrow = lane & 15, lgrp = lane >> 4;

    // A-frags: lane holds A[row=lane&15][k=(lane>>4)*8+i]; two point-sets s,
    // two K-chunks kk (D=64 = 2x32).
    f16x8 a[2][2];
#pragma unroll
    for (int s = 0; s < 2; ++s)
#pragma unroll
        for (int kk = 0; kk < 2; ++kk) {
            const float4* p = (const float4*)(x + (size_t)(pbase + s * 16 + lrow) * DD
                                              + kk * 32 + lgrp * 8);
            float4 u0 = p[0], u1 = p[1];
            f16x8 t;
            t[0] = (_Float16)u0.x; t[1] = (_Float16)u0.y;
            t[2] = (_Float16)u0.z; t[3] = (_Float16)u0.w;
            t[4] = (_Float16)u1.x; t[5] = (_Float16)u1.y;
            t[6] = (_Float16)u1.z; t[7] = (_Float16)u1.w;
            a[s][kk] = t;
        }

    unsigned b1[2][4], b2[2][4];
#pragma unroll
    for (int s = 0; s < 2; ++s)
#pragma unroll
        for (int r = 0; r < 4; ++r) { b1[s][r] = 0xFFFFFFFFu; b2[s][r] = 0xFFFFFFFFu; }

    // B-frag LDS address: row=cent, slot = kk*4+lgrp, swizzled by (cent&7)=(lane&7).
    int base0 = lrow * 128 + ((lgrp ^ (lane & 7)) << 4);       // kk=0
    int base1 = base0 ^ 64;                                    // slot+4 == slot^4 pre-XOR
    int centv = lrow;

    for (int ct = 0; ct < 32; ++ct) {
        f16x8 bk0 = *(const f16x8*)(smem + base0);
        f16x8 bk1 = *(const f16x8*)(smem + base1);
        float cs = scs[centv];
        f32x4 acc0 = {0.f, 0.f, 0.f, 0.f}, acc1 = {0.f, 0.f, 0.f, 0.f};
        acc0 = __builtin_amdgcn_mfma_f32_16x16x32_f16(a[0][0], bk0, acc0, 0, 0, 0);
        acc0 = __builtin_amdgcn_mfma_f32_16x16x32_f16(a[0][1], bk1, acc0, 0, 0, 0);
        acc1 = __builtin_amdgcn_mfma_f32_16x16x32_f16(a[1][0], bk0, acc1, 0, 0, 0);
        acc1 = __builtin_amdgcn_mfma_f32_16x16x32_f16(a[1][1], bk1, acc1, 0, 0, 0);
#pragma unroll
        for (int r = 0; r < 4; ++r) {
            float d0 = __builtin_fmaf(-2.0f, acc0[r], cs);
            float d1 = __builtin_fmaf(-2.0f, acc1[r], cs);
            unsigned k0 = (__float_as_uint(d0) & 0xFFFFFE00u) | (unsigned)centv;
            unsigned k1 = (__float_as_uint(d1) & 0xFFFFFE00u) | (unsigned)centv;
            unsigned m0 = max(b1[0][r], k0);
            b1[0][r] = min(b1[0][r], k0);
            b2[0][r] = min(b2[0][r], m0);
            unsigned m1 = max(b1[1][r], k1);
            b1[1][r] = min(b1[1][r], k1);
            b2[1][r] = min(b2[1][r], m1);
        }
        base0 += 2048; base1 += 2048; centv += 16;
    }

    // Merge best-2 across the 16 lanes of each row-group (xor butterfly).
#pragma unroll
    for (int d = 1; d < 16; d <<= 1) {
#pragma unroll
        for (int s = 0; s < 2; ++s)
#pragma unroll
            for (int r = 0; r < 4; ++r) {
                unsigned o1 = (unsigned)__shfl_xor((int)b1[s][r], d);
                unsigned o2 = (unsigned)__shfl_xor((int)b2[s][r], d);
                unsigned mx = max(b1[s][r], o1);
                b1[s][r] = min(b1[s][r], o1);
                b2[s][r] = min(min(b2[s][r], o2), mx);
            }
    }

    if (lrow == 0) {
#pragma unroll
        for (int s = 0; s < 2; ++s)
#pragma unroll
            for (int r = 0; r < 4; ++r) {
                int p = pbase + s * 16 + lgrp * 4 + r;     // C/D row = (lane>>4)*4+reg
                unsigned w = b1[s][r];
                out_assign[p] = (float)(w & 0x1FFu);
                float d1 = __uint_as_float(w & 0xFFFFFE00u);
                float d2 = __uint_as_float(b2[s][r] & 0xFFFFFE00u);
                if (d2 - d1 <= MARGIN) {
                    int idx = atomicAdd(cnt, 1);
                    if (idx < list_cap) list[idx] = p;
                }
            }
    }
}

// Exact rescore of flagged points: bit-identical to the R1 kernel (absmax=0).
__global__ __launch_bounds__(256) void cleanup_kernel(const float* __restrict__ x,
                                                      const float* __restrict__ c,
                                                      const float* __restrict__ csq,
                                                      const int* __restrict__ cnt,
                                                      const int* __restrict__ list,
                                                      int list_cap,
                                                      float* __restrict__ out_assign) {
    int n = min(*cnt, list_cap);
    for (int idx = blockIdx.x * 256 + threadIdx.x; idx < n; idx += 256 * 256) {
        int i = list[idx];
        float xv[DD];
        const float4* xp = (const float4*)(x + (size_t)i * DD);
#pragma unroll
        for (int q = 0; q < DD / 4; ++q) {
            float4 v = xp[q];
            xv[4 * q + 0] = v.x; xv[4 * q + 1] = v.y;
            xv[4 * q + 2] = v.z; xv[4 * q + 3] = v.w;
        }
        float r[8];
#pragma unroll
        for (int t = 0; t < 8; ++t) r[t] = __fmul_rn(xv[t], xv[t]);
#pragma unroll
        for (int b = 1; b < 8; ++b)
#pragma unroll
            for (int t = 0; t < 8; ++t)
                r[t] = __fadd_rn(r[t], __fmul_rn(xv[8 * b + t], xv[8 * b + t]));
        float x_sq = __fadd_rn(__fadd_rn(__fadd_rn(r[0], r[1]), __fadd_rn(r[2], r[3])),
                               __fadd_rn(__fadd_rn(r[4], r[5]), __fadd_rn(r[6], r[7])));
        float best = INFINITY;
        int best_k = 0;
        for (int k = 0; k < KC; ++k) {
            const float* crow = c + (size_t)k * DD;  // wave-uniform -> s_load
            float a0 = 0.f, a1 = 0.f, a2 = 0.f, a3 = 0.f;
#pragma unroll
            for (int d = 0; d < DD; d += 4) {
                a0 = __fmaf_rn(xv[d + 0], crow[d + 0], a0);
                a1 = __fmaf_rn(xv[d + 1], crow[d + 1], a1);
                a2 = __fmaf_rn(xv[d + 2], crow[d + 2], a2);
                a3 = __fmaf_rn(xv[d + 3], crow[d + 3], a3);
            }
            float acc = __fadd_rn(__fadd_rn(a0, a1), __fadd_rn(a2, a3));
            float t = __fadd_rn(x_sq, csq[k]);
            float dist = __fmaf_rn(-2.0f, acc, t);
            if (dist < best) { best = dist; best_k = k; }  // strict <: first wins
        }
        out_assign[i] = (float)best_k;
    }
}

extern "C" void kernel_launch(void* const* d_in, const int* in_sizes, int n_in,
                              void* d_out, int out_size, void* d_ws, size_t ws_size,
                              hipStream_t stream) {
    const float* x = (const float*)d_in[0];
    const float* c = (const float*)d_in[1];
    float* out = (float*)d_out;
    float* out_assign = out + KC * DD;

    char* ws = (char*)d_ws;
    int* cnt = (int*)(ws + WS_CNT);
    float* cs16 = (float*)(ws + WS_CS16);
    float* csq = (float*)(ws + WS_CSQ);
    _Float16* cf16 = (_Float16*)(ws + WS_CF16);
    int* list = (int*)(ws + WS_LIST);
    int list_cap = 0;
    if (ws_size > WS_LIST + 4) {
        size_t cap = (ws_size - WS_LIST) / 4;
        list_cap = cap > NPTS ? NPTS : (int)cap;
    }

    hipMemsetAsync(cnt, 0, 16, stream);
    prep_kernel<<<(KC * DD + 255) / 256, 256, 0, stream>>>(c, out, cf16, cs16, csq);
    approx_kernel<<<NPTS / 128, 256, 67584, stream>>>(x, cf16, cs16, out_assign,
                                                      cnt, list, list_cap);
    cleanup_kernel<<<256, 256, 0, stream>>>(x, c, csq, cnt, list, list_cap, out_assign);
}

// Round 6
// 159.666 us; speedup vs baseline: 3.0702x; 3.0702x over previous
//
#include <hip/hip_runtime.h>
#include <math.h>

#define NPTS 262144
#define KC 512
#define DD 64
#define MARGIN 1e-3f
#define LOSCALE 2048.0f
#define INV2LO 0.0009765625f   // 2 / LOSCALE = 2^-10
#define SLICE 128

typedef _Float16 f16x8 __attribute__((ext_vector_type(8)));
typedef _Float16 f16x4 __attribute__((ext_vector_type(4)));
typedef float f32x4 __attribute__((ext_vector_type(4)));

__device__ __forceinline__ float csq_pairwise8(const float* row) {
    float r[8];
#pragma unroll
    for (int t = 0; t < 8; ++t) r[t] = __fmul_rn(row[t], row[t]);
#pragma unroll
    for (int b = 1; b < 8; ++b)
#pragma unroll
        for (int t = 0; t < 8; ++t)
            r[t] = __fadd_rn(r[t], __fmul_rn(row[8 * b + t], row[8 * b + t]));
    return __fadd_rn(__fadd_rn(__fadd_rn(r[0], r[1]), __fadd_rn(r[2], r[3])),
                     __fadd_rn(__fadd_rn(r[4], r[5]), __fadd_rn(r[6], r[7])));
}

// Prep: centroid passthrough + exact c_sq (numpy pairwise-8 order).
__global__ __launch_bounds__(256) void prep_kernel(const float* __restrict__ c,
                                                   float* __restrict__ out_c,
                                                   float* __restrict__ csq) {
    int j = blockIdx.x * 256 + threadIdx.x;
    if (j < KC * DD) out_c[j] = c[j];
    if (j < KC) csq[j] = csq_pairwise8(c + j * DD);
}

// Single fused kernel: split-f16 MFMA approximate distances; ambiguous points
// (top-2 gap <= MARGIN) rescored EXACTLY in-kernel (np-replica bit-exact code).
// Every out_assign element has exactly ONE writer per launch; the only d_ws
// state is csq (2 KB) -> no cross-kernel scratch, no ws-size hazard (the R5
// failure mode: 1 MB unguarded blk_list overflowing ws between validation
// and graph timing).
__global__ __launch_bounds__(256, 2) void approx_kernel(const float* __restrict__ x,
                                                        const float* __restrict__ c,
                                                        const float* __restrict__ csq,
                                                        float* __restrict__ out_assign) {
    extern __shared__ char smem[];          // [0,32K) c_hi | [32K,64K) c_lo'
    float* scs = (float*)(smem + 65536);    // 512 f32
    int* llist = (int*)(smem + 67584);      // 128 int flagged point ids
    int* lcnt = (int*)(smem + 68096);

    int tid = threadIdx.x;
    if (tid == 0) *lcnt = 0;
    scs[tid] = csq[tid];
    scs[tid + 256] = csq[tid + 256];

    int wid = tid >> 6, lane = tid & 63;
    int lrow = lane & 15, lgrp = lane >> 4;
    int pbase = blockIdx.x * 128 + wid * 32;

    // A fragments (layout verified absmax=0 in R4/R5): row=lane&15,
    // k-elems kk*32+lgrp*8. Split x = hi + lo'/2048 (lo' f16-normal).
    f16x8 ahi[2][2], alo[2][2];
#pragma unroll
    for (int s = 0; s < 2; ++s)
#pragma unroll
        for (int kk = 0; kk < 2; ++kk) {
            const float4* p = (const float4*)(x + (size_t)(pbase + s * 16 + lrow) * DD
                                              + kk * 32 + lgrp * 8);
            float4 u0 = p[0], u1 = p[1];
            float f[8] = {u0.x, u0.y, u0.z, u0.w, u1.x, u1.y, u1.z, u1.w};
            f16x8 h, l;
#pragma unroll
            for (int e = 0; e < 8; ++e) {
                _Float16 hh = (_Float16)f[e];
                h[e] = hh;
                l[e] = (_Float16)((f[e] - (float)hh) * LOSCALE);
            }
            ahi[s][kk] = h;
            alo[s][kk] = l;
        }

    float b1[2][4], b2[2][4];
    int k1[2][4];
#pragma unroll
    for (int s = 0; s < 2; ++s)
#pragma unroll
        for (int r = 0; r < 4; ++r) { b1[s][r] = INFINITY; b2[s][r] = INFINITY; k1[s][r] = 0; }

    for (int pass = 0; pass < 2; ++pass) {
        __syncthreads();   // covers scs/lcnt staging on pass 0; pass-0 reads on pass 1
        // Stage 256 centroid rows: fp32 -> (hi, lo') f16, XOR-swizzled.
        const float4* csrc = (const float4*)(c + (size_t)pass * 256 * DD);
#pragma unroll
        for (int it = 0; it < 16; ++it) {
            int chunk = tid + it * 256;                 // 4096 x 16B-src chunks
            int row = chunk >> 4, q = chunk & 15;
            float4 v = csrc[chunk];
            f16x4 h, l;
            _Float16 t;
            t = (_Float16)v.x; h[0] = t; l[0] = (_Float16)((v.x - (float)t) * LOSCALE);
            t = (_Float16)v.y; h[1] = t; l[1] = (_Float16)((v.y - (float)t) * LOSCALE);
            t = (_Float16)v.z; h[2] = t; l[2] = (_Float16)((v.z - (float)t) * LOSCALE);
            t = (_Float16)v.w; h[3] = t; l[3] = (_Float16)((v.w - (float)t) * LOSCALE);
            int off = row * 128 + (((q >> 1) ^ (row & 7)) << 4) + (q & 1) * 8;
            *(f16x4*)(smem + off) = h;
            *(f16x4*)(smem + 32768 + off) = l;
        }
        __syncthreads();

        int base0 = lrow * 128 + ((lgrp ^ (lrow & 7)) << 4);
        int csi = pass * 256 + lrow;
#pragma unroll 2
        for (int ct = 0; ct < 16; ++ct) {
            f16x8 bh0 = *(const f16x8*)(smem + base0);
            f16x8 bh1 = *(const f16x8*)(smem + (base0 ^ 64));
            f16x8 bl0 = *(const f16x8*)(smem + 32768 + base0);
            f16x8 bl1 = *(const f16x8*)(smem + 32768 + (base0 ^ 64));
            float cs = scs[csi];
            int kv = csi;
#pragma unroll
            for (int s = 0; s < 2; ++s) {
                f32x4 hh = {0.f, 0.f, 0.f, 0.f}, cr = {0.f, 0.f, 0.f, 0.f};
                hh = __builtin_amdgcn_mfma_f32_16x16x32_f16(ahi[s][0], bh0, hh, 0, 0, 0);
                hh = __builtin_amdgcn_mfma_f32_16x16x32_f16(ahi[s][1], bh1, hh, 0, 0, 0);
                cr = __builtin_amdgcn_mfma_f32_16x16x32_f16(ahi[s][0], bl0, cr, 0, 0, 0);
                cr = __builtin_amdgcn_mfma_f32_16x16x32_f16(ahi[s][1], bl1, cr, 0, 0, 0);
                cr = __builtin_amdgcn_mfma_f32_16x16x32_f16(alo[s][0], bh0, cr, 0, 0, 0);
                cr = __builtin_amdgcn_mfma_f32_16x16x32_f16(alo[s][1], bh1, cr, 0, 0, 0);
#pragma unroll
                for (int r = 0; r < 4; ++r) {
                    float d = __fmaf_rn(-INV2LO, cr[r], __fmaf_rn(-2.0f, hh[r], cs));
                    bool lt = d < b1[s][r];
                    b2[s][r] = fminf(b2[s][r], fmaxf(b1[s][r], d));
                    b1[s][r] = fminf(b1[s][r], d);
                    k1[s][r] = lt ? kv : k1[s][r];
                }
            }
            base0 += 2048;
            csi += 16;
        }
    }

    // Merge best-2 across the 16 lanes of each row-group. Cross-lane ties leave
    // gap==0 -> flagged -> exact rescore, so tie k-direction is free.
#pragma unroll
    for (int dd = 1; dd < 16; dd <<= 1)
#pragma unroll
        for (int s = 0; s < 2; ++s)
#pragma unroll
            for (int r = 0; r < 4; ++r) {
                float o1 = __shfl_xor(b1[s][r], dd);
                float o2 = __shfl_xor(b2[s][r], dd);
                int ok = __shfl_xor(k1[s][r], dd);
                b2[s][r] = fminf(fminf(b2[s][r], o2), fmaxf(b1[s][r], o1));
                bool lt = o1 < b1[s][r];
                b1[s][r] = fminf(b1[s][r], o1);
                k1[s][r] = lt ? ok : k1[s][r];
            }

    // Flag phase: flagged points go ONLY to llist (no approx write -> exactly
    // one writer per output element); unflagged written here.
    if (lrow == 0) {
#pragma unroll
        for (int s = 0; s < 2; ++s)
#pragma unroll
            for (int r = 0; r < 4; ++r) {
                int p = pbase + s * 16 + lgrp * 4 + r;   // C/D row=(lane>>4)*4+reg
                if (b2[s][r] - b1[s][r] <= MARGIN) {
                    int t = atomicAdd(lcnt, 1);          // LDS atomic only
                    if (t < SLICE) llist[t] = p;
                } else {
                    out_assign[p] = (float)k1[s][r];
                }
            }
    }
    __syncthreads();

    // In-kernel exact rescore: one WAVE per flagged point, lanes own 8
    // centroids each. Bit-identical np-replica distance (proven absmax=0).
    // First-index-wins via packed (distbits<<32)|k min (dist > 0: ||x||>>||c||).
    int n = *lcnt;
    if (n > SLICE) n = SLICE;
    for (int t = wid; t < n; t += 4) {
        int i = __builtin_amdgcn_readfirstlane(llist[t]);
        const float* xr = x + (size_t)i * DD;   // wave-uniform -> s_loads

        float r8[8];
#pragma unroll
        for (int e = 0; e < 8; ++e) r8[e] = __fmul_rn(xr[e], xr[e]);
#pragma unroll
        for (int blk = 1; blk < 8; ++blk)
#pragma unroll
            for (int e = 0; e < 8; ++e)
                r8[e] = __fadd_rn(r8[e], __fmul_rn(xr[8 * blk + e], xr[8 * blk + e]));
        float x_sq = __fadd_rn(__fadd_rn(__fadd_rn(r8[0], r8[1]), __fadd_rn(r8[2], r8[3])),
                               __fadd_rn(__fadd_rn(r8[4], r8[5]), __fadd_rn(r8[6], r8[7])));

        unsigned long long best = ~0ull;
#pragma unroll
        for (int j = 0; j < 8; ++j) {
            int k = j * 64 + lane;
            const float* crow = c + (size_t)k * DD;
            float a0 = 0.f, a1 = 0.f, a2 = 0.f, a3 = 0.f;
#pragma unroll
            for (int d = 0; d < DD; d += 4) {
                a0 = __fmaf_rn(xr[d + 0], crow[d + 0], a0);
                a1 = __fmaf_rn(xr[d + 1], crow[d + 1], a1);
                a2 = __fmaf_rn(xr[d + 2], crow[d + 2], a2);
                a3 = __fmaf_rn(xr[d + 3], crow[d + 3], a3);
            }
            float acc = __fadd_rn(__fadd_rn(a0, a1), __fadd_rn(a2, a3));
            float tt = __fadd_rn(x_sq, csq[k]);
            float dist = __fmaf_rn(-2.0f, acc, tt);
            unsigned long long key =
                ((unsigned long long)__float_as_uint(dist) << 32) | (unsigned)k;
            best = best < key ? best : key;
        }
#pragma unroll
        for (int dd = 1; dd < 64; dd <<= 1) {
            unsigned hi = (unsigned)__shfl_xor((int)(best >> 32), dd);
            unsigned lo = (unsigned)__shfl_xor((int)(best & 0xFFFFFFFFull), dd);
            unsigned long long o = ((unsigned long long)hi << 32) | lo;
            best = best < o ? best : o;
        }
        if (lane == 0) out_assign[i] = (float)(unsigned)(best & 0xFFFFFFFFull);
    }
}

extern "C" void kernel_launch(void* const* d_in, const int* in_sizes, int n_in,
                              void* d_out, int out_size, void* d_ws, size_t ws_size,
                              hipStream_t stream) {
    const float* x = (const float*)d_in[0];
    const float* c = (const float*)d_in[1];
    float* out = (float*)d_out;
    float* out_assign = out + KC * DD;
    float* csq = (float*)d_ws;   // 2048 bytes of d_ws, nothing else

    prep_kernel<<<(KC * DD + 255) / 256, 256, 0, stream>>>(c, out, csq);
    approx_kernel<<<NPTS / 128, 256, 68112, stream>>>(x, c, csq, out_assign);
}